// Round 13
// baseline (622.432 us; speedup 1.0000x reference)
//
#include <hip/hip_runtime.h>
#include <stdint.h>

// Problem constants
#define BATCH 4096
#define DIMD  256
#define DIMH  1024
#define NEEL  10485760   // E elements per stage: 10*4096*256
#define NSLOT 1310720    // NEEL/8: short8 slots per stage

typedef __attribute__((ext_vector_type(8))) short short8;
typedef __attribute__((ext_vector_type(4))) float float4v;

struct Keys4 { uint32_t a[4]; uint32_t b[4]; };

// ---------------- threefry2x32 (JAX-compatible, 20 rounds) ----------------
__host__ __device__ static inline uint32_t rotl32(uint32_t v, int r) {
#ifdef __HIP_DEVICE_COMPILE__
    return __builtin_amdgcn_alignbit(v, v, 32 - r);   // 1-inst funnel rotate
#else
    return (v << r) | (v >> (32 - r));
#endif
}

__host__ __device__ static inline void tf2x32(uint32_t k0, uint32_t k1,
                                              uint32_t c0, uint32_t c1,
                                              uint32_t& o0, uint32_t& o1) {
    uint32_t ks0 = k0, ks1 = k1, ks2 = k0 ^ k1 ^ 0x1BD11BDAu;
    uint32_t x0 = c0 + ks0, x1 = c1 + ks1;
#define TF_R4(a, b, c, d)                                   \
    x0 += x1; x1 = rotl32(x1, a); x1 ^= x0;                 \
    x0 += x1; x1 = rotl32(x1, b); x1 ^= x0;                 \
    x0 += x1; x1 = rotl32(x1, c); x1 ^= x0;                 \
    x0 += x1; x1 = rotl32(x1, d); x1 ^= x0;
    TF_R4(13, 15, 26, 6)  x0 += ks1; x1 += ks2 + 1u;
    TF_R4(17, 29, 16, 24) x0 += ks2; x1 += ks0 + 2u;
    TF_R4(13, 15, 26, 6)  x0 += ks0; x1 += ks1 + 3u;
    TF_R4(17, 29, 16, 24) x0 += ks1; x1 += ks2 + 4u;
    TF_R4(13, 15, 26, 6)  x0 += ks2; x1 += ks0 + 5u;
#undef TF_R4
    o0 = x0; o1 = x1;
}

// float -> bf16 (round-to-nearest-even), bit pattern in a short
__device__ static inline short f2bf(float f) {
    uint32_t u = __float_as_uint(f);
    uint32_t r = (u + 0x7FFFu + ((u >> 16) & 1u)) >> 16;
    return (short)r;
}

// E fragment-layout egen: slot q (a short8) covers elements of
//   probe = q>>17, T = (q>>9)&255, ks = (q>>6)&7, lane = q&63, jj = 0..7
//   -> batch row b = T*16 + (lane&15), d = ks*32 + (lane>>4)*8 + jj
//   -> threefry counter j = (probe*4096 + b)*256 + d  (consecutive in jj).
// JAX partitionable threefry: bit = (y0^y1)&1; e = bit ? +1 : -1 (bf16).
__device__ static inline void egen_slot(short* __restrict__ EF, uint32_t q,
                                        uint32_t k0, uint32_t k1) {
    const uint32_t lane = q & 63u;
    const uint32_t ks   = (q >> 6) & 7u;
    const uint32_t T    = (q >> 9) & 255u;
    const uint32_t probe = q >> 17;
    const uint32_t b = T * 16u + (lane & 15u);
    const uint32_t d0 = ks * 32u + (lane >> 4) * 8u;
    const uint32_t jbase = (probe * 4096u + b) * 256u + d0;
    short8 val;
#pragma unroll
    for (int jj = 0; jj < 8; ++jj) {
        uint32_t y0, y1;
        tf2x32(k0, k1, 0u, jbase + (uint32_t)jj, y0, y1);
        val[jj] = ((y0 ^ y1) & 1u) ? (short)0x3F80 : (short)0xBF80u;
    }
    *(short8*)&EF[(size_t)q * 8] = val;
}

// ---------------- Prep (fused): W1T, W2B, W2T, Zb0, dv=0, E0 frags --------
__global__ __launch_bounds__(256) void k_prep(
    const float* __restrict__ x,  const float* __restrict__ W1,
    const float* __restrict__ W2, short* __restrict__ W1T,
    short* __restrict__ W2B, short* __restrict__ W2T,
    short* __restrict__ zb, float* __restrict__ dv,
    short* __restrict__ E0, uint32_t ek0, uint32_t ek1)
{
    const int idx = blockIdx.x * 256 + threadIdx.x;
    if (idx < 262144) {                       // W1T[n][d] = bf16(W1[d][n])
        const int n = idx >> 8, d = idx & 255;
        W1T[idx] = f2bf(W1[d * DIMH + n]);
    } else if (idx < 524288) {                // W2B = bf16(W2) row-major
        const int i = idx - 262144;
        W2B[i] = f2bf(W2[i]);
    } else if (idx < 786432) {                // W2T[d][k] = bf16(W2[k][d])
        const int i = idx - 524288;
        const int d = i >> 10, k = i & 1023;
        W2T[i] = f2bf(W2[k * DIMD + d]);
    } else if (idx < 1835008) {               // zb0 = bf16(x)
        const int i = idx - 786432;
        zb[i] = f2bf(x[i]);
    } else if (idx < 1851392) {               // dv = 0 (4*4096 floats)
        dv[idx - 1835008] = 0.0f;
    } else {                                  // E0 fragments: 1.31M slots
        egen_slot(E0, (uint32_t)(idx - 1851392), ek0, ek1);
    }
}

// ---------------- Fused K1+K3: h-tile + probes (frag-E, probe-split) ------
// Grid (64 batch-tiles, 32): y = phalf*16 + nt. blockIdx.x = batch tile so
// all 32 blocks sharing one E slice get the same flat%8 -> same XCD.
// 256 thr = 4 waves; wave owns one 16-wide n-subtile.
// Probe split (R13): phalf in {0,1} handles probes phalf*5..+5 — doubles
// resident blocks/CU (4 -> 8 queued; ~24 waves/CU at VGPR<=85) to cover
// the E-load latency that capped R12 at 26% occupancy. h-phase recomputed
// by both halves (+0.9 µs chip MFMA); only phalf=0 writes hb.
__global__ __launch_bounds__(256) void k_pre_div(
    const short* __restrict__ Zb, const short* __restrict__ W1T,
    const short* __restrict__ W2B, const float* __restrict__ W1,
    const float* __restrict__ b1, float tval,
    const short* __restrict__ Ecur, short* __restrict__ h_bf,
    float* __restrict__ divacc,
    short* __restrict__ Enext, uint32_t nk0, uint32_t nk1, int do_egen)
{
    const int t = threadIdx.x;
    const int b0 = blockIdx.x * 64;
    const int nt = blockIdx.y & 15;
    const int phalf = blockIdx.y >> 4;
    const int wave = t >> 6, lane = t & 63;
    const int col = lane & 15, kq = lane >> 4;
    const int n = nt * 64 + wave * 16 + col;

    // B-fragments, once per kernel
    short8 bufr[8], bvfr[8];
#pragma unroll
    for (int ks = 0; ks < 8; ++ks) {
        bufr[ks] = *(const short8*)&W1T[n * DIMD + ks * 32 + kq * 8];
        bvfr[ks] = *(const short8*)&W2B[n * DIMD + ks * 32 + kq * 8];
    }

    // ---- Phase 1: h = tanh(Zb @ W1T^T + t*W1[256] + b1) ----
    float sreg[4][4];
    const float add = tval * W1[DIMD * DIMH + n] + b1[n];
#pragma unroll
    for (int ms = 0; ms < 4; ++ms) {
        float4v acc = {0.f, 0.f, 0.f, 0.f};
#pragma unroll
        for (int ks = 0; ks < 8; ++ks) {
            short8 af = *(const short8*)&Zb[(b0 + ms * 16 + col) * DIMD + ks * 32 + kq * 8];
            acc = __builtin_amdgcn_mfma_f32_16x16x32_bf16(af, bufr[ks], acc, 0, 0, 0);
        }
        // C layout: col = lane&15, row = kq*4 + r (verified m89/m91)
#pragma unroll
        for (int r = 0; r < 4; ++r) {
            float hv = tanhf(acc[r] + add);
            if (phalf == 0)
                h_bf[(b0 + ms * 16 + kq * 4 + r) * DIMH + n] = f2bf(hv);
            sreg[ms][r] = 1.0f - hv * hv;
        }
    }

    float rowacc[4][4];
#pragma unroll
    for (int a = 0; a < 4; ++a)
#pragma unroll
        for (int r = 0; r < 4; ++r) rowacc[a][r] = 0.0f;

    // egen share: linear id over 2048 blocks x 256 thr = 524288 threads;
    // slots q = lid + k*524288, k = 0..2 (k=2 valid for lid < 262144).
    const uint32_t lid = (uint32_t)(blockIdx.y * 64 + blockIdx.x) * 256u + (uint32_t)t;

    const int Tb = b0 >> 4;   // base m-tile index for this block

    // ---- Probe loop (5 probes): barrier-free, A-frags from frag-E ----
#pragma unroll 1
    for (int pp = 0; pp < 5; ++pp) {
        const int probe = phalf * 5 + pp;
        // next-stage egen interleaved at pp = 0, 2, 4
        if (do_egen && (pp & 1) == 0) {
            uint32_t q = lid + (uint32_t)(pp >> 1) * 524288u;
            if (q < (uint32_t)NSLOT) egen_slot(Enext, q, nk0, nk1);
        }
#pragma unroll
        for (int ms = 0; ms < 4; ++ms) {
            // base short8 index: (((probe*256 + Tb+ms)*8 + 0)*64 + lane)
            const short8* ap = (const short8*)Ecur +
                ((size_t)(probe * 256 + Tb + ms) * 8) * 64 + lane;
            short8 af[8];
#pragma unroll
            for (int ks = 0; ks < 8; ++ks) af[ks] = ap[ks * 64];
            float4v u = {0.f, 0.f, 0.f, 0.f}, v = {0.f, 0.f, 0.f, 0.f};
#pragma unroll
            for (int ks = 0; ks < 8; ++ks) {
                u = __builtin_amdgcn_mfma_f32_16x16x32_bf16(af[ks], bufr[ks], u, 0, 0, 0);
                v = __builtin_amdgcn_mfma_f32_16x16x32_bf16(af[ks], bvfr[ks], v, 0, 0, 0);
            }
#pragma unroll
            for (int r = 0; r < 4; ++r)
                rowacc[ms][r] += u[r] * sreg[ms][r] * v[r];
        }
    }

#pragma unroll
    for (int ms = 0; ms < 4; ++ms) {
#pragma unroll
        for (int r = 0; r < 4; ++r) {
            float p = rowacc[ms][r];
            p += __shfl_xor(p, 1, 64);
            p += __shfl_xor(p, 2, 64);
            p += __shfl_xor(p, 4, 64);
            p += __shfl_xor(p, 8, 64);
            rowacc[ms][r] = p;
        }
    }
    if (col == 0) {
#pragma unroll
        for (int ms = 0; ms < 4; ++ms)
#pragma unroll
            for (int r = 0; r < 4; ++r)
                atomicAdd(&divacc[b0 + ms * 16 + kq * 4 + r], rowacc[ms][r] * 0.1f);
    }
}

// ---------------- K2: fz = Hb @ W2 + b2; rksum += cw*fz; fuse Zb_next -----
// MFMA 16x16x32, K=1024 pipelined. Block 256 thr = 4 waves; wave = 16 rows
// x 64 cols (waves tile N=256). Grid = 4096/16 = 256.
__global__ __launch_bounds__(256) void k_fz2(
    const short* __restrict__ Hb, const short* __restrict__ W2T,
    const float* __restrict__ b2, const float* __restrict__ x,
    float* __restrict__ rksum, float cw, int first,
    float cnext, int write_zb, short* __restrict__ zb)
{
    const int t = threadIdx.x;
    const int wave = t >> 6, lane = t & 63;
    const int col = lane & 15, kq = lane >> 4;
    const int m0 = blockIdx.x * 16;
    const int n0 = wave * 64;

    float4v acc[4];
#pragma unroll
    for (int ns = 0; ns < 4; ++ns) acc[ns] = (float4v){0.f, 0.f, 0.f, 0.f};

    const short* ap = &Hb[(m0 + col) * DIMH + kq * 8];
    short8 a_cur = *(const short8*)ap;
    short8 b_cur[4];
#pragma unroll
    for (int ns = 0; ns < 4; ++ns)
        b_cur[ns] = *(const short8*)&W2T[(n0 + ns * 16 + col) * DIMH + kq * 8];

    for (int ks = 0; ks < 31; ++ks) {
        short8 a_nxt = *(const short8*)&ap[(ks + 1) * 32];
        short8 b_nxt[4];
#pragma unroll
        for (int ns = 0; ns < 4; ++ns)
            b_nxt[ns] = *(const short8*)&W2T[(n0 + ns * 16 + col) * DIMH + (ks + 1) * 32 + kq * 8];
#pragma unroll
        for (int ns = 0; ns < 4; ++ns)
            acc[ns] = __builtin_amdgcn_mfma_f32_16x16x32_bf16(a_cur, b_cur[ns], acc[ns], 0, 0, 0);
        a_cur = a_nxt;
#pragma unroll
        for (int ns = 0; ns < 4; ++ns) b_cur[ns] = b_nxt[ns];
    }
#pragma unroll
    for (int ns = 0; ns < 4; ++ns)
        acc[ns] = __builtin_amdgcn_mfma_f32_16x16x32_bf16(a_cur, b_cur[ns], acc[ns], 0, 0, 0);

#pragma unroll
    for (int ns = 0; ns < 4; ++ns) {
        const int n = n0 + ns * 16 + col;
        const float bias = b2[n];
#pragma unroll
        for (int r = 0; r < 4; ++r) {
            const int m = m0 + kq * 4 + r;
            const int o = m * DIMD + n;
            const float val = acc[ns][r] + bias;
            const float contrib = cw * val;
            rksum[o] = first ? contrib : (rksum[o] + contrib);
            if (write_zb)
                zb[o] = f2bf(x[o] + cnext * val);
        }
    }
}

// ---------------- K4: RK4 combine + output --------------------------------
__global__ __launch_bounds__(256) void k_out(
    const float* __restrict__ x, const float* __restrict__ rksum,
    const float* __restrict__ divacc, float* __restrict__ out)
{
    const int idx = blockIdx.x * 256 + threadIdx.x;
    const int TOT = BATCH * (DIMD + 1);
    if (idx >= TOT) return;
    const int b = idx / (DIMD + 1);
    const int c = idx - b * (DIMD + 1);
    const float sixth = 1.0f / 6.0f;
    if (c < DIMD) {
        float xv = x[b * DIMD + c];
        out[idx] = xv;
        out[TOT + idx] = xv + rksum[b * DIMD + c] * sixth;
    } else {
        float d1 = divacc[b];
        float d2 = divacc[BATCH + b];
        float d3 = divacc[2 * BATCH + b];
        float d4 = divacc[3 * BATCH + b];
        out[idx] = 0.0f;
        out[TOT + idx] = -(d1 + 2.0f * d2 + 2.0f * d3 + d4) * sixth;
    }
}

// ---------------- launch ---------------------------------------------------
extern "C" void kernel_launch(void* const* d_in, const int* in_sizes, int n_in,
                              void* d_out, int out_size, void* d_ws, size_t ws_size,
                              hipStream_t stream) {
    const float* x  = (const float*)d_in[0];
    const float* W1 = (const float*)d_in[1];
    const float* b1 = (const float*)d_in[2];
    const float* W2 = (const float*)d_in[3];
    const float* b2 = (const float*)d_in[4];
    float* out = (float*)d_out;

    char* ws = (char*)d_ws;
    short* hb    = (short*)(ws);                   // 8 MiB
    float* rksum = (float*)(ws + 8388608);         // 4 MiB
    short* zb    = (short*)(ws + 12582912);        // 2 MiB
    short* w1t   = (short*)(ws + 14680064);        // 512 KiB
    short* w2b   = (short*)(ws + 15204352);        // 512 KiB
    short* w2t   = (short*)(ws + 15728640);        // 512 KiB
    float* dv    = (float*)(ws + 16252928);        // 64 KiB
    short* e0    = (short*)(ws + 16318464);        // 20 MiB (frag E, ping)
    short* e1    = (short*)(ws + 37289984);        // 20 MiB (frag E, pong)
    // total 58261504 B ~= 55.6 MiB (fit verified by R11/R12 runs)

    // Host-side threefry key derivation (partitionable semantics):
    //   fk_i = tf((0,42),(0,i));  k2_i = tf(fk_i,(0,1))
    Keys4 keys;
    for (uint32_t i = 0; i < 4; ++i) {
        uint32_t f0, f1, g0, g1;
        tf2x32(0u, 42u, 0u, i, f0, f1);
        tf2x32(f0, f1, 0u, 1u, g0, g1);
        keys.a[i] = g0;
        keys.b[i] = g1;
    }

    // 1851392 prep items + 1310720 E0 slots = 3162112 = 12352*256
    k_prep<<<12352, 256, 0, stream>>>(x, W1, W2, w1t, w2b, w2t, zb, dv,
                                      e0, keys.a[0], keys.b[0]);

    const float tvals[4] = {0.0f, 0.5f, 0.5f, 1.0f};
    const float cnext[4] = {0.5f, 0.5f, 1.0f, 0.0f};  // Zb_{s+1} = x + cnext*fz_s
    const float cw[4]    = {1.0f, 2.0f, 2.0f, 1.0f};  // RK4 weights
    for (int s = 0; s < 4; ++s) {
        const int last = (s == 3);
        short* ecur = (s & 1) ? e1 : e0;
        short* enxt = (s & 1) ? e0 : e1;
        k_pre_div<<<dim3(64, 32), 256, 0, stream>>>(
            zb, w1t, w2b, W1, b1, tvals[s], ecur,
            hb, dv + (size_t)s * BATCH,
            enxt, last ? 0u : keys.a[s + 1], last ? 0u : keys.b[s + 1],
            last ? 0 : 1);
        k_fz2<<<256, 256, 0, stream>>>(hb, w2t, b2, x, rksum,
                                       cw[s], (s == 0) ? 1 : 0,
                                       cnext[s], (s < 3) ? 1 : 0, zb);
    }
    int tot = BATCH * (DIMD + 1);
    k_out<<<(tot + 255) / 256, 256, 0, stream>>>(x, rksum, dv, out);
}

// Round 14
// 496.702 us; speedup vs baseline: 1.2531x; 1.2531x over previous
//
#include <hip/hip_runtime.h>
#include <stdint.h>

// Problem constants
#define BATCH 4096
#define DIMD  256
#define DIMH  1024
#define NEEL  10485760   // E elements per stage: 10*4096*256
#define NSLOT 1310720    // NEEL/8: short8 slots per stage

typedef __attribute__((ext_vector_type(8))) short short8;
typedef __attribute__((ext_vector_type(4))) float float4v;

struct Keys4 { uint32_t a[4]; uint32_t b[4]; };

// ---------------- threefry2x32 (JAX-compatible, 20 rounds) ----------------
__host__ __device__ static inline uint32_t rotl32(uint32_t v, int r) {
#ifdef __HIP_DEVICE_COMPILE__
    return __builtin_amdgcn_alignbit(v, v, 32 - r);   // 1-inst funnel rotate
#else
    return (v << r) | (v >> (32 - r));
#endif
}

__host__ __device__ static inline void tf2x32(uint32_t k0, uint32_t k1,
                                              uint32_t c0, uint32_t c1,
                                              uint32_t& o0, uint32_t& o1) {
    uint32_t ks0 = k0, ks1 = k1, ks2 = k0 ^ k1 ^ 0x1BD11BDAu;
    uint32_t x0 = c0 + ks0, x1 = c1 + ks1;
#define TF_R4(a, b, c, d)                                   \
    x0 += x1; x1 = rotl32(x1, a); x1 ^= x0;                 \
    x0 += x1; x1 = rotl32(x1, b); x1 ^= x0;                 \
    x0 += x1; x1 = rotl32(x1, c); x1 ^= x0;                 \
    x0 += x1; x1 = rotl32(x1, d); x1 ^= x0;
    TF_R4(13, 15, 26, 6)  x0 += ks1; x1 += ks2 + 1u;
    TF_R4(17, 29, 16, 24) x0 += ks2; x1 += ks0 + 2u;
    TF_R4(13, 15, 26, 6)  x0 += ks0; x1 += ks1 + 3u;
    TF_R4(17, 29, 16, 24) x0 += ks1; x1 += ks2 + 4u;
    TF_R4(13, 15, 26, 6)  x0 += ks2; x1 += ks0 + 5u;
#undef TF_R4
    o0 = x0; o1 = x1;
}

// float -> bf16 (round-to-nearest-even), bit pattern in a short
__device__ static inline short f2bf(float f) {
    uint32_t u = __float_as_uint(f);
    uint32_t r = (u + 0x7FFFu + ((u >> 16) & 1u)) >> 16;
    return (short)r;
}

// E fragment-layout egen: slot q (a short8) covers elements of
//   probe = q>>17, T = (q>>9)&255, ks = (q>>6)&7, lane = q&63, jj = 0..7
//   -> batch row b = T*16 + (lane&15), d = ks*32 + (lane>>4)*8 + jj
//   -> threefry counter j = (probe*4096 + b)*256 + d  (consecutive in jj).
// JAX partitionable threefry: bit = (y0^y1)&1; e = bit ? +1 : -1 (bf16).
__device__ static inline void egen_slot(short* __restrict__ EF, uint32_t q,
                                        uint32_t k0, uint32_t k1) {
    const uint32_t lane = q & 63u;
    const uint32_t ks   = (q >> 6) & 7u;
    const uint32_t T    = (q >> 9) & 255u;
    const uint32_t probe = q >> 17;
    const uint32_t b = T * 16u + (lane & 15u);
    const uint32_t d0 = ks * 32u + (lane >> 4) * 8u;
    const uint32_t jbase = (probe * 4096u + b) * 256u + d0;
    short8 val;
#pragma unroll
    for (int jj = 0; jj < 8; ++jj) {
        uint32_t y0, y1;
        tf2x32(k0, k1, 0u, jbase + (uint32_t)jj, y0, y1);
        val[jj] = ((y0 ^ y1) & 1u) ? (short)0x3F80 : (short)0xBF80u;
    }
    *(short8*)&EF[(size_t)q * 8] = val;
}

// ---------------- Prep (fused): W1T, W2B, W2T, Zb0, dv=0, E0 frags --------
__global__ __launch_bounds__(256) void k_prep(
    const float* __restrict__ x,  const float* __restrict__ W1,
    const float* __restrict__ W2, short* __restrict__ W1T,
    short* __restrict__ W2B, short* __restrict__ W2T,
    short* __restrict__ zb, float* __restrict__ dv,
    short* __restrict__ E0, uint32_t ek0, uint32_t ek1)
{
    const int idx = blockIdx.x * 256 + threadIdx.x;
    if (idx < 262144) {                       // W1T[n][d] = bf16(W1[d][n])
        const int n = idx >> 8, d = idx & 255;
        W1T[idx] = f2bf(W1[d * DIMH + n]);
    } else if (idx < 524288) {                // W2B = bf16(W2) row-major
        const int i = idx - 262144;
        W2B[i] = f2bf(W2[i]);
    } else if (idx < 786432) {                // W2T[d][k] = bf16(W2[k][d])
        const int i = idx - 524288;
        const int d = i >> 10, k = i & 1023;
        W2T[i] = f2bf(W2[k * DIMD + d]);
    } else if (idx < 1835008) {               // zb0 = bf16(x)
        const int i = idx - 786432;
        zb[i] = f2bf(x[i]);
    } else if (idx < 1851392) {               // dv = 0 (4*4096 floats)
        dv[idx - 1835008] = 0.0f;
    } else {                                  // E0 fragments: 1.31M slots
        egen_slot(E0, (uint32_t)(idx - 1851392), ek0, ek1);
    }
}

// ---------------- Fused K1+K3: h-tile + probes (frag-E, LDS-staged) -------
// R12 grid restored: (64 batch-tiles, 16 n-tiles); blockIdx.x = batch tile
// so the 16 nt-blocks sharing one E slice map to the same XCD. 256 thr =
// 4 waves; wave owns one 16-wide n-subtile.
// R14 change: per probe, the block's E slice (one contiguous 32 KB region
// in fragment order) is staged into LDS with copy-only b128 transfers —
// the 4 waves' A-frags then come from LDS, cutting the 4x intra-block L2
// redundancy that made R12's E traffic 1.34 GB/stage (~39 µs of L2 time).
// No PRNG expansion in LDS (that was R8's cost) — pure memcpy.
__global__ __launch_bounds__(256) void k_pre_div(
    const short* __restrict__ Zb, const short* __restrict__ W1T,
    const short* __restrict__ W2B, const float* __restrict__ W1,
    const float* __restrict__ b1, float tval,
    const short* __restrict__ Ecur, short* __restrict__ h_bf,
    float* __restrict__ divacc,
    short* __restrict__ Enext, uint32_t nk0, uint32_t nk1, int do_egen)
{
    __shared__ short8 Es[2048];        // 32 KB: one probe's E slice
    const int t = threadIdx.x;
    const int b0 = blockIdx.x * 64;
    const int nt = blockIdx.y;
    const int wave = t >> 6, lane = t & 63;
    const int col = lane & 15, kq = lane >> 4;
    const int n = nt * 64 + wave * 16 + col;

    // B-fragments, once per kernel
    short8 bufr[8], bvfr[8];
#pragma unroll
    for (int ks = 0; ks < 8; ++ks) {
        bufr[ks] = *(const short8*)&W1T[n * DIMD + ks * 32 + kq * 8];
        bvfr[ks] = *(const short8*)&W2B[n * DIMD + ks * 32 + kq * 8];
    }

    // ---- Phase 1: h = tanh(Zb @ W1T^T + t*W1[256] + b1) ----
    float sreg[4][4];
    const float add = tval * W1[DIMD * DIMH + n] + b1[n];
#pragma unroll
    for (int ms = 0; ms < 4; ++ms) {
        float4v acc = {0.f, 0.f, 0.f, 0.f};
#pragma unroll
        for (int ks = 0; ks < 8; ++ks) {
            short8 af = *(const short8*)&Zb[(b0 + ms * 16 + col) * DIMD + ks * 32 + kq * 8];
            acc = __builtin_amdgcn_mfma_f32_16x16x32_bf16(af, bufr[ks], acc, 0, 0, 0);
        }
        // C layout: col = lane&15, row = kq*4 + r (verified m89/m91)
#pragma unroll
        for (int r = 0; r < 4; ++r) {
            float hv = tanhf(acc[r] + add);
            h_bf[(b0 + ms * 16 + kq * 4 + r) * DIMH + n] = f2bf(hv);
            sreg[ms][r] = 1.0f - hv * hv;
        }
    }

    float rowacc[4][4];
#pragma unroll
    for (int a = 0; a < 4; ++a)
#pragma unroll
        for (int r = 0; r < 4; ++r) rowacc[a][r] = 0.0f;

    // egen share (R12 mapping): 5 slots/thread on even probes
    const uint32_t bflat = (uint32_t)(blockIdx.y * 64 + blockIdx.x);   // 0..1023
    const uint32_t qbase = bflat * 256u + (uint32_t)t;

    const int Tb = b0 >> 4;   // base m-tile index for this block

    // ---- Probe loop: LDS-staged A-frags, 2 barriers/probe ----
#pragma unroll 1
    for (int probe = 0; probe < 10; ++probe) {
        if (do_egen && (probe & 1) == 0) {
            egen_slot(Enext, qbase + (uint32_t)(probe >> 1) * 262144u, nk0, nk1);
        }
        // stage this probe's 32 KB slice: slots [(probe*256+Tb)*512, +2048)
        const short8* src = (const short8*)Ecur + (size_t)(probe * 256 + Tb) * 512;
        __syncthreads();   // previous probe's readers done before overwrite
#pragma unroll
        for (int k = 0; k < 8; ++k)
            Es[t + k * 256] = src[t + k * 256];
        __syncthreads();

#pragma unroll
        for (int ms = 0; ms < 4; ++ms) {
            float4v u = {0.f, 0.f, 0.f, 0.f}, v = {0.f, 0.f, 0.f, 0.f};
#pragma unroll
            for (int ks = 0; ks < 8; ++ks) {
                short8 af = Es[((ms * 8 + ks) << 6) + lane];
                u = __builtin_amdgcn_mfma_f32_16x16x32_bf16(af, bufr[ks], u, 0, 0, 0);
                v = __builtin_amdgcn_mfma_f32_16x16x32_bf16(af, bvfr[ks], v, 0, 0, 0);
            }
#pragma unroll
            for (int r = 0; r < 4; ++r)
                rowacc[ms][r] += u[r] * sreg[ms][r] * v[r];
        }
    }

#pragma unroll
    for (int ms = 0; ms < 4; ++ms) {
#pragma unroll
        for (int r = 0; r < 4; ++r) {
            float p = rowacc[ms][r];
            p += __shfl_xor(p, 1, 64);
            p += __shfl_xor(p, 2, 64);
            p += __shfl_xor(p, 4, 64);
            p += __shfl_xor(p, 8, 64);
            rowacc[ms][r] = p;
        }
    }
    if (col == 0) {
#pragma unroll
        for (int ms = 0; ms < 4; ++ms)
#pragma unroll
            for (int r = 0; r < 4; ++r)
                atomicAdd(&divacc[b0 + ms * 16 + kq * 4 + r], rowacc[ms][r] * 0.1f);
    }
}

// ---------------- K2: fz = Hb @ W2 + b2; rksum += cw*fz; fuse Zb_next -----
// MFMA 16x16x32, K=1024 pipelined. Block 256 thr = 4 waves; wave = 16 rows
// x 64 cols (waves tile N=256). Grid = 4096/16 = 256.
__global__ __launch_bounds__(256) void k_fz2(
    const short* __restrict__ Hb, const short* __restrict__ W2T,
    const float* __restrict__ b2, const float* __restrict__ x,
    float* __restrict__ rksum, float cw, int first,
    float cnext, int write_zb, short* __restrict__ zb)
{
    const int t = threadIdx.x;
    const int wave = t >> 6, lane = t & 63;
    const int col = lane & 15, kq = lane >> 4;
    const int m0 = blockIdx.x * 16;
    const int n0 = wave * 64;

    float4v acc[4];
#pragma unroll
    for (int ns = 0; ns < 4; ++ns) acc[ns] = (float4v){0.f, 0.f, 0.f, 0.f};

    const short* ap = &Hb[(m0 + col) * DIMH + kq * 8];
    short8 a_cur = *(const short8*)ap;
    short8 b_cur[4];
#pragma unroll
    for (int ns = 0; ns < 4; ++ns)
        b_cur[ns] = *(const short8*)&W2T[(n0 + ns * 16 + col) * DIMH + kq * 8];

    for (int ks = 0; ks < 31; ++ks) {
        short8 a_nxt = *(const short8*)&ap[(ks + 1) * 32];
        short8 b_nxt[4];
#pragma unroll
        for (int ns = 0; ns < 4; ++ns)
            b_nxt[ns] = *(const short8*)&W2T[(n0 + ns * 16 + col) * DIMH + (ks + 1) * 32 + kq * 8];
#pragma unroll
        for (int ns = 0; ns < 4; ++ns)
            acc[ns] = __builtin_amdgcn_mfma_f32_16x16x32_bf16(a_cur, b_cur[ns], acc[ns], 0, 0, 0);
        a_cur = a_nxt;
#pragma unroll
        for (int ns = 0; ns < 4; ++ns) b_cur[ns] = b_nxt[ns];
    }
#pragma unroll
    for (int ns = 0; ns < 4; ++ns)
        acc[ns] = __builtin_amdgcn_mfma_f32_16x16x32_bf16(a_cur, b_cur[ns], acc[ns], 0, 0, 0);

#pragma unroll
    for (int ns = 0; ns < 4; ++ns) {
        const int n = n0 + ns * 16 + col;
        const float bias = b2[n];
#pragma unroll
        for (int r = 0; r < 4; ++r) {
            const int m = m0 + kq * 4 + r;
            const int o = m * DIMD + n;
            const float val = acc[ns][r] + bias;
            const float contrib = cw * val;
            rksum[o] = first ? contrib : (rksum[o] + contrib);
            if (write_zb)
                zb[o] = f2bf(x[o] + cnext * val);
        }
    }
}

// ---------------- K4: RK4 combine + output --------------------------------
__global__ __launch_bounds__(256) void k_out(
    const float* __restrict__ x, const float* __restrict__ rksum,
    const float* __restrict__ divacc, float* __restrict__ out)
{
    const int idx = blockIdx.x * 256 + threadIdx.x;
    const int TOT = BATCH * (DIMD + 1);
    if (idx >= TOT) return;
    const int b = idx / (DIMD + 1);
    const int c = idx - b * (DIMD + 1);
    const float sixth = 1.0f / 6.0f;
    if (c < DIMD) {
        float xv = x[b * DIMD + c];
        out[idx] = xv;
        out[TOT + idx] = xv + rksum[b * DIMD + c] * sixth;
    } else {
        float d1 = divacc[b];
        float d2 = divacc[BATCH + b];
        float d3 = divacc[2 * BATCH + b];
        float d4 = divacc[3 * BATCH + b];
        out[idx] = 0.0f;
        out[TOT + idx] = -(d1 + 2.0f * d2 + 2.0f * d3 + d4) * sixth;
    }
}

// ---------------- launch ---------------------------------------------------
extern "C" void kernel_launch(void* const* d_in, const int* in_sizes, int n_in,
                              void* d_out, int out_size, void* d_ws, size_t ws_size,
                              hipStream_t stream) {
    const float* x  = (const float*)d_in[0];
    const float* W1 = (const float*)d_in[1];
    const float* b1 = (const float*)d_in[2];
    const float* W2 = (const float*)d_in[3];
    const float* b2 = (const float*)d_in[4];
    float* out = (float*)d_out;

    char* ws = (char*)d_ws;
    short* hb    = (short*)(ws);                   // 8 MiB
    float* rksum = (float*)(ws + 8388608);         // 4 MiB
    short* zb    = (short*)(ws + 12582912);        // 2 MiB
    short* w1t   = (short*)(ws + 14680064);        // 512 KiB
    short* w2b   = (short*)(ws + 15204352);        // 512 KiB
    short* w2t   = (short*)(ws + 15728640);        // 512 KiB
    float* dv    = (float*)(ws + 16252928);        // 64 KiB
    short* e0    = (short*)(ws + 16318464);        // 20 MiB (frag E, ping)
    short* e1    = (short*)(ws + 37289984);        // 20 MiB (frag E, pong)
    // total 58261504 B ~= 55.6 MiB (fit verified by R11/R12 runs)

    // Host-side threefry key derivation (partitionable semantics):
    //   fk_i = tf((0,42),(0,i));  k2_i = tf(fk_i,(0,1))
    Keys4 keys;
    for (uint32_t i = 0; i < 4; ++i) {
        uint32_t f0, f1, g0, g1;
        tf2x32(0u, 42u, 0u, i, f0, f1);
        tf2x32(f0, f1, 0u, 1u, g0, g1);
        keys.a[i] = g0;
        keys.b[i] = g1;
    }

    // 1851392 prep items + 1310720 E0 slots = 3162112 = 12352*256
    k_prep<<<12352, 256, 0, stream>>>(x, W1, W2, w1t, w2b, w2t, zb, dv,
                                      e0, keys.a[0], keys.b[0]);

    const float tvals[4] = {0.0f, 0.5f, 0.5f, 1.0f};
    const float cnext[4] = {0.5f, 0.5f, 1.0f, 0.0f};  // Zb_{s+1} = x + cnext*fz_s
    const float cw[4]    = {1.0f, 2.0f, 2.0f, 1.0f};  // RK4 weights
    for (int s = 0; s < 4; ++s) {
        const int last = (s == 3);
        short* ecur = (s & 1) ? e1 : e0;
        short* enxt = (s & 1) ? e0 : e1;
        k_pre_div<<<dim3(64, 16), 256, 0, stream>>>(
            zb, w1t, w2b, W1, b1, tvals[s], ecur,
            hb, dv + (size_t)s * BATCH,
            enxt, last ? 0u : keys.a[s + 1], last ? 0u : keys.b[s + 1],
            last ? 0 : 1);
        k_fz2<<<256, 256, 0, stream>>>(hb, w2t, b2, x, rksum,
                                       cw[s], (s == 0) ? 1 : 0,
                                       cnext[s], (s < 3) ? 1 : 0, zb);
    }
    int tot = BATCH * (DIMD + 1);
    k_out<<<(tot + 255) / 256, 256, 0, stream>>>(x, rksum, dv, out);
}

// Round 16
// 482.995 us; speedup vs baseline: 1.2887x; 1.0284x over previous
//
#include <hip/hip_runtime.h>
#include <stdint.h>

// Problem constants
#define BATCH 4096
#define DIMD  256
#define DIMH  1024
#define NEEL  10485760   // E elements per stage: 10*4096*256
#define NSLOT 1310720    // NEEL/8: short8 slots per stage

typedef __attribute__((ext_vector_type(8))) short short8;
typedef __attribute__((ext_vector_type(4))) float float4v;

struct Keys4 { uint32_t a[4]; uint32_t b[4]; };

// ---------------- threefry2x32 (JAX-compatible, 20 rounds) ----------------
__host__ __device__ static inline uint32_t rotl32(uint32_t v, int r) {
#ifdef __HIP_DEVICE_COMPILE__
    return __builtin_amdgcn_alignbit(v, v, 32 - r);   // 1-inst funnel rotate
#else
    return (v << r) | (v >> (32 - r));
#endif
}

__host__ __device__ static inline void tf2x32(uint32_t k0, uint32_t k1,
                                              uint32_t c0, uint32_t c1,
                                              uint32_t& o0, uint32_t& o1) {
    uint32_t ks0 = k0, ks1 = k1, ks2 = k0 ^ k1 ^ 0x1BD11BDAu;
    uint32_t x0 = c0 + ks0, x1 = c1 + ks1;
#define TF_R4(a, b, c, d)                                   \
    x0 += x1; x1 = rotl32(x1, a); x1 ^= x0;                 \
    x0 += x1; x1 = rotl32(x1, b); x1 ^= x0;                 \
    x0 += x1; x1 = rotl32(x1, c); x1 ^= x0;                 \
    x0 += x1; x1 = rotl32(x1, d); x1 ^= x0;
    TF_R4(13, 15, 26, 6)  x0 += ks1; x1 += ks2 + 1u;
    TF_R4(17, 29, 16, 24) x0 += ks2; x1 += ks0 + 2u;
    TF_R4(13, 15, 26, 6)  x0 += ks0; x1 += ks1 + 3u;
    TF_R4(17, 29, 16, 24) x0 += ks1; x1 += ks2 + 4u;
    TF_R4(13, 15, 26, 6)  x0 += ks2; x1 += ks0 + 5u;
#undef TF_R4
    o0 = x0; o1 = x1;
}

// float -> bf16 (round-to-nearest-even), bit pattern in a short
__device__ static inline short f2bf(float f) {
    uint32_t u = __float_as_uint(f);
    uint32_t r = (u + 0x7FFFu + ((u >> 16) & 1u)) >> 16;
    return (short)r;
}

// E fragment-layout egen: slot q (a short8) covers elements of
//   probe = q>>17, T = (q>>9)&255, ks = (q>>6)&7, lane = q&63, jj = 0..7
//   -> batch row b = T*16 + (lane&15), d = ks*32 + (lane>>4)*8 + jj
//   -> threefry counter j = (probe*4096 + b)*256 + d  (consecutive in jj).
// JAX partitionable threefry: bit = (y0^y1)&1; e = bit ? +1 : -1 (bf16).
__device__ static inline void egen_slot(short* __restrict__ EF, uint32_t q,
                                        uint32_t k0, uint32_t k1) {
    const uint32_t lane = q & 63u;
    const uint32_t ks   = (q >> 6) & 7u;
    const uint32_t T    = (q >> 9) & 255u;
    const uint32_t probe = q >> 17;
    const uint32_t b = T * 16u + (lane & 15u);
    const uint32_t d0 = ks * 32u + (lane >> 4) * 8u;
    const uint32_t jbase = (probe * 4096u + b) * 256u + d0;
    short8 val;
#pragma unroll
    for (int jj = 0; jj < 8; ++jj) {
        uint32_t y0, y1;
        tf2x32(k0, k1, 0u, jbase + (uint32_t)jj, y0, y1);
        val[jj] = ((y0 ^ y1) & 1u) ? (short)0x3F80 : (short)0xBF80u;
    }
    *(short8*)&EF[(size_t)q * 8] = val;
}

// ---------------- Prep (fused): W1T, W2B, W2T, Zb0, dv=0, E0 frags --------
__global__ __launch_bounds__(256) void k_prep(
    const float* __restrict__ x,  const float* __restrict__ W1,
    const float* __restrict__ W2, short* __restrict__ W1T,
    short* __restrict__ W2B, short* __restrict__ W2T,
    short* __restrict__ zb, float* __restrict__ dv,
    short* __restrict__ E0, uint32_t ek0, uint32_t ek1)
{
    const int idx = blockIdx.x * 256 + threadIdx.x;
    if (idx < 262144) {                       // W1T[n][d] = bf16(W1[d][n])
        const int n = idx >> 8, d = idx & 255;
        W1T[idx] = f2bf(W1[d * DIMH + n]);
    } else if (idx < 524288) {                // W2B = bf16(W2) row-major
        const int i = idx - 262144;
        W2B[i] = f2bf(W2[i]);
    } else if (idx < 786432) {                // W2T[d][k] = bf16(W2[k][d])
        const int i = idx - 524288;
        const int d = i >> 10, k = i & 1023;
        W2T[i] = f2bf(W2[k * DIMD + d]);
    } else if (idx < 1835008) {               // zb0 = bf16(x)
        const int i = idx - 786432;
        zb[i] = f2bf(x[i]);
    } else if (idx < 1851392) {               // dv = 0 (4*4096 floats)
        dv[idx - 1835008] = 0.0f;
    } else {                                  // E0 fragments: 1.31M slots
        egen_slot(E0, (uint32_t)(idx - 1851392), ek0, ek1);
    }
}

// ---------------- Fused K1+K3: h-tile + probes (frag-E, pair-staged) ------
// R14 grid: (64 batch-tiles, 16 n-tiles); blockIdx.x = batch tile so the
// 16 nt-blocks sharing one E slice map to the same XCD. 256 thr = 4 waves.
// R16 change: stage TWO probe slices (64 KB LDS) per barrier pair ->
// 10 barriers instead of 20 (R14 counters: barrier drain was ~40 µs of the
// 86; LDS floor ~32 µs). 64 KB LDS is free: measured residency was already
// 2 blocks/CU (unified VGPR+AGPR pressure — R14 Occupancy 23%).
__global__ __launch_bounds__(256) void k_pre_div(
    const short* __restrict__ Zb, const short* __restrict__ W1T,
    const short* __restrict__ W2B, const float* __restrict__ W1,
    const float* __restrict__ b1, float tval,
    const short* __restrict__ Ecur, short* __restrict__ h_bf,
    float* __restrict__ divacc,
    short* __restrict__ Enext, uint32_t nk0, uint32_t nk1, int do_egen)
{
    __shared__ short8 Es[4096];        // 64 KB: two probes' E slices
    const int t = threadIdx.x;
    const int b0 = blockIdx.x * 64;
    const int nt = blockIdx.y;
    const int wave = t >> 6, lane = t & 63;
    const int col = lane & 15, kq = lane >> 4;
    const int n = nt * 64 + wave * 16 + col;

    // B-fragments, once per kernel
    short8 bufr[8], bvfr[8];
#pragma unroll
    for (int ks = 0; ks < 8; ++ks) {
        bufr[ks] = *(const short8*)&W1T[n * DIMD + ks * 32 + kq * 8];
        bvfr[ks] = *(const short8*)&W2B[n * DIMD + ks * 32 + kq * 8];
    }

    // ---- Phase 1: h = tanh(Zb @ W1T^T + t*W1[256] + b1) ----
    float sreg[4][4];
    const float add = tval * W1[DIMD * DIMH + n] + b1[n];
#pragma unroll
    for (int ms = 0; ms < 4; ++ms) {
        float4v acc = {0.f, 0.f, 0.f, 0.f};
#pragma unroll
        for (int ks = 0; ks < 8; ++ks) {
            short8 af = *(const short8*)&Zb[(b0 + ms * 16 + col) * DIMD + ks * 32 + kq * 8];
            acc = __builtin_amdgcn_mfma_f32_16x16x32_bf16(af, bufr[ks], acc, 0, 0, 0);
        }
        // C layout: col = lane&15, row = kq*4 + r (verified m89/m91)
#pragma unroll
        for (int r = 0; r < 4; ++r) {
            float hv = tanhf(acc[r] + add);
            h_bf[(b0 + ms * 16 + kq * 4 + r) * DIMH + n] = f2bf(hv);
            sreg[ms][r] = 1.0f - hv * hv;
        }
    }

    float rowacc[4][4];
#pragma unroll
    for (int a = 0; a < 4; ++a)
#pragma unroll
        for (int r = 0; r < 4; ++r) rowacc[a][r] = 0.0f;

    // egen share: 5 slots/thread, one per probe-pair (same q mapping as R14)
    const uint32_t bflat = (uint32_t)(blockIdx.y * 64 + blockIdx.x);   // 0..1023
    const uint32_t qbase = bflat * 256u + (uint32_t)t;

    const int Tb = b0 >> 4;   // base m-tile index for this block

    // ---- Probe-pair loop: 2 slices staged per barrier pair ----
#pragma unroll 1
    for (int pp = 0; pp < 5; ++pp) {
        if (do_egen) {
            egen_slot(Enext, qbase + (uint32_t)pp * 262144u, nk0, nk1);
        }
        // slices for probes 2*pp and 2*pp+1: slots [(p*256+Tb)*512, +2048)
        const short8* src0 = (const short8*)Ecur + (size_t)((2 * pp) * 256 + Tb) * 512;
        const short8* src1 = src0 + (size_t)256 * 512;
        __syncthreads();   // previous pair's readers done before overwrite
#pragma unroll
        for (int k = 0; k < 8; ++k)
            Es[t + k * 256] = src0[t + k * 256];
#pragma unroll
        for (int k = 0; k < 8; ++k)
            Es[2048 + t + k * 256] = src1[t + k * 256];
        __syncthreads();

#pragma unroll
        for (int half = 0; half < 2; ++half) {
#pragma unroll
            for (int ms = 0; ms < 4; ++ms) {
                float4v u = {0.f, 0.f, 0.f, 0.f}, v = {0.f, 0.f, 0.f, 0.f};
#pragma unroll
                for (int ks = 0; ks < 8; ++ks) {
                    short8 af = Es[half * 2048 + ((ms * 8 + ks) << 6) + lane];
                    u = __builtin_amdgcn_mfma_f32_16x16x32_bf16(af, bufr[ks], u, 0, 0, 0);
                    v = __builtin_amdgcn_mfma_f32_16x16x32_bf16(af, bvfr[ks], v, 0, 0, 0);
                }
#pragma unroll
                for (int r = 0; r < 4; ++r)
                    rowacc[ms][r] += u[r] * sreg[ms][r] * v[r];
            }
        }
    }

#pragma unroll
    for (int ms = 0; ms < 4; ++ms) {
#pragma unroll
        for (int r = 0; r < 4; ++r) {
            float p = rowacc[ms][r];
            p += __shfl_xor(p, 1, 64);
            p += __shfl_xor(p, 2, 64);
            p += __shfl_xor(p, 4, 64);
            p += __shfl_xor(p, 8, 64);
            rowacc[ms][r] = p;
        }
    }
    if (col == 0) {
#pragma unroll
        for (int ms = 0; ms < 4; ++ms)
#pragma unroll
            for (int r = 0; r < 4; ++r)
                atomicAdd(&divacc[b0 + ms * 16 + kq * 4 + r], rowacc[ms][r] * 0.1f);
    }
}

// ---------------- K2: fz = Hb @ W2 + b2; rksum/out; fuse Zb_next ----------
// MFMA 16x16x32, K=1024. Block 256 thr = 4 waves; wave = 16 rows x 64 cols.
// Grid = 256. s<3: rksum += cw*fz, zb_next = bf16(x + cnext*fz).
// s==3 (final_out): writes the OUTPUT directly (k_out merged): y0 = x,
// y1 = x + (rksum + fz4)/6; div column via wave-3 col==0 lanes (dv complete
// because pre_div s3 precedes this kernel).
__global__ __launch_bounds__(256) void k_fz2(
    const short* __restrict__ Hb, const short* __restrict__ W2T,
    const float* __restrict__ b2, const float* __restrict__ x,
    float* __restrict__ rksum, float cw, int first,
    float cnext, int write_zb, short* __restrict__ zb,
    int final_out, const float* __restrict__ dv, float* __restrict__ out)
{
    const int t = threadIdx.x;
    const int wave = t >> 6, lane = t & 63;
    const int col = lane & 15, kq = lane >> 4;
    const int m0 = blockIdx.x * 16;
    const int n0 = wave * 64;
    const int TOT = BATCH * (DIMD + 1);
    const float sixth = 1.0f / 6.0f;

    float4v acc[4];
#pragma unroll
    for (int ns = 0; ns < 4; ++ns) acc[ns] = (float4v){0.f, 0.f, 0.f, 0.f};

    const short* ap = &Hb[(m0 + col) * DIMH + kq * 8];
    short8 a_cur = *(const short8*)ap;
    short8 b_cur[4];
#pragma unroll
    for (int ns = 0; ns < 4; ++ns)
        b_cur[ns] = *(const short8*)&W2T[(n0 + ns * 16 + col) * DIMH + kq * 8];

    for (int ks = 0; ks < 31; ++ks) {
        short8 a_nxt = *(const short8*)&ap[(ks + 1) * 32];
        short8 b_nxt[4];
#pragma unroll
        for (int ns = 0; ns < 4; ++ns)
            b_nxt[ns] = *(const short8*)&W2T[(n0 + ns * 16 + col) * DIMH + (ks + 1) * 32 + kq * 8];
#pragma unroll
        for (int ns = 0; ns < 4; ++ns)
            acc[ns] = __builtin_amdgcn_mfma_f32_16x16x32_bf16(a_cur, b_cur[ns], acc[ns], 0, 0, 0);
        a_cur = a_nxt;
#pragma unroll
        for (int ns = 0; ns < 4; ++ns) b_cur[ns] = b_nxt[ns];
    }
#pragma unroll
    for (int ns = 0; ns < 4; ++ns)
        acc[ns] = __builtin_amdgcn_mfma_f32_16x16x32_bf16(a_cur, b_cur[ns], acc[ns], 0, 0, 0);

#pragma unroll
    for (int ns = 0; ns < 4; ++ns) {
        const int n = n0 + ns * 16 + col;
        const float bias = b2[n];
#pragma unroll
        for (int r = 0; r < 4; ++r) {
            const int m = m0 + kq * 4 + r;
            const int o = m * DIMD + n;
            const float val = acc[ns][r] + bias;
            if (final_out) {
                const float xv = x[o];
                out[m * (DIMD + 1) + n] = xv;                          // y0 z
                out[TOT + m * (DIMD + 1) + n] =
                    xv + (rksum[o] + val) * sixth;                     // y1 z
            } else {
                const float contrib = cw * val;
                rksum[o] = first ? contrib : (rksum[o] + contrib);
                if (write_zb)
                    zb[o] = f2bf(x[o] + cnext * val);
            }
        }
    }

    // div column (c = 256): 16 rows of this block, handled by wave 3's
    // col==0 lanes (4 lanes x 4 regs = 16 rows).
    if (final_out && wave == 3 && col == 0) {
#pragma unroll
        for (int r = 0; r < 4; ++r) {
            const int m = m0 + kq * 4 + r;
            const float d1 = dv[m];
            const float d2 = dv[BATCH + m];
            const float d3 = dv[2 * BATCH + m];
            const float d4 = dv[3 * BATCH + m];
            out[m * (DIMD + 1) + DIMD] = 0.0f;                         // y0 div
            out[TOT + m * (DIMD + 1) + DIMD] =
                -(d1 + 2.0f * d2 + 2.0f * d3 + d4) * sixth;            // y1 div
        }
    }
}

// ---------------- launch ---------------------------------------------------
extern "C" void kernel_launch(void* const* d_in, const int* in_sizes, int n_in,
                              void* d_out, int out_size, void* d_ws, size_t ws_size,
                              hipStream_t stream) {
    const float* x  = (const float*)d_in[0];
    const float* W1 = (const float*)d_in[1];
    const float* b1 = (const float*)d_in[2];
    const float* W2 = (const float*)d_in[3];
    const float* b2 = (const float*)d_in[4];
    float* out = (float*)d_out;

    char* ws = (char*)d_ws;
    short* hb    = (short*)(ws);                   // 8 MiB
    float* rksum = (float*)(ws + 8388608);         // 4 MiB
    short* zb    = (short*)(ws + 12582912);        // 2 MiB
    short* w1t   = (short*)(ws + 14680064);        // 512 KiB
    short* w2b   = (short*)(ws + 15204352);        // 512 KiB
    short* w2t   = (short*)(ws + 15728640);        // 512 KiB
    float* dv    = (float*)(ws + 16252928);        // 64 KiB
    short* e0    = (short*)(ws + 16318464);        // 20 MiB (frag E, ping)
    short* e1    = (short*)(ws + 37289984);        // 20 MiB (frag E, pong)
    // total 58261504 B ~= 55.6 MiB (fit verified by R11-R14 runs)

    // Host-side threefry key derivation (partitionable semantics):
    //   fk_i = tf((0,42),(0,i));  k2_i = tf(fk_i,(0,1))
    Keys4 keys;
    for (uint32_t i = 0; i < 4; ++i) {
        uint32_t f0, f1, g0, g1;
        tf2x32(0u, 42u, 0u, i, f0, f1);
        tf2x32(f0, f1, 0u, 1u, g0, g1);
        keys.a[i] = g0;
        keys.b[i] = g1;
    }

    // 1851392 prep items + 1310720 E0 slots = 3162112 = 12352*256
    k_prep<<<12352, 256, 0, stream>>>(x, W1, W2, w1t, w2b, w2t, zb, dv,
                                      e0, keys.a[0], keys.b[0]);

    const float tvals[4] = {0.0f, 0.5f, 0.5f, 1.0f};
    const float cnext[4] = {0.5f, 0.5f, 1.0f, 0.0f};  // Zb_{s+1} = x + cnext*fz_s
    const float cw[4]    = {1.0f, 2.0f, 2.0f, 1.0f};  // RK4 weights
    for (int s = 0; s < 4; ++s) {
        const int last = (s == 3);
        short* ecur = (s & 1) ? e1 : e0;
        short* enxt = (s & 1) ? e0 : e1;
        k_pre_div<<<dim3(64, 16), 256, 0, stream>>>(
            zb, w1t, w2b, W1, b1, tvals[s], ecur,
            hb, dv + (size_t)s * BATCH,
            enxt, last ? 0u : keys.a[s + 1], last ? 0u : keys.b[s + 1],
            last ? 0 : 1);
        k_fz2<<<256, 256, 0, stream>>>(hb, w2t, b2, x, rksum,
                                       cw[s], (s == 0) ? 1 : 0,
                                       cnext[s], (s < 3) ? 1 : 0, zb,
                                       last ? 1 : 0, dv, out);
    }
}